// Round 11
// baseline (111.791 us; speedup 1.0000x reference)
//
#include <hip/hip_runtime.h>
#include <hip/hip_bf16.h>
#include <math.h>

#define BATCH 32
#define LEN   2048
#define HID   128
#define SSM   256

static const size_t PLz = 16777216;   // elements per state plane (32*256*2048)
#define BPL 32768                     // elements per B-split plane (256*128)
#define CPL 32768                     // elements per C-split plane (128*256)

typedef __attribute__((ext_vector_type(4))) float f32x4;
typedef __attribute__((ext_vector_type(8))) short bf16x8;
typedef __attribute__((ext_vector_type(4))) short bf16x4;
typedef __attribute__((ext_vector_type(4))) int   i32x4;
typedef __attribute__((ext_vector_type(2))) unsigned int u32x2;

// RNE f32->bf16 (bit trick)
static __device__ __forceinline__ unsigned short f2bf(float x) {
    union { float f; unsigned u; } v; v.f = x;
    unsigned r = (v.u + 0x7FFFu + ((v.u >> 16) & 1u)) >> 16;
    return (unsigned short)r;
}
// truncating f32->bf16 (hi term of split; lo captures remainder exactly)
static __device__ __forceinline__ unsigned short f2bf_hi(float x) {
    union { float f; unsigned u; } v; v.f = x;
    return (unsigned short)(v.u >> 16);
}
static __device__ __forceinline__ float bf2f(unsigned short b) {
    union { unsigned u; float f; } v; v.u = ((unsigned)b) << 16;
    return v.f;
}
// packed RNE pair convert -> one u32 (v_cvt_pk_bf16_f32)
static __device__ __forceinline__ unsigned int cvtpk(float a, float b) {
    __hip_bfloat162 h = __float22bfloat162_rn(float2{a, b});
    union { __hip_bfloat162 h2; unsigned int u; } c; c.h2 = h;
    return c.u;
}
static __device__ __forceinline__ void cmul(float& rr, float& ri,
                                            float ar, float ai, float br, float bi) {
    rr = ar * br - ai * bi;
    ri = ar * bi + ai * br;
}
// async global->LDS 16B (zero VGPR round-trip; vmcnt-counted)
static __device__ __forceinline__ void gload16(const void* g, void* l) {
    __builtin_amdgcn_global_load_lds(
        (const __attribute__((address_space(1))) unsigned int*)g,
        (__attribute__((address_space(3))) unsigned int*)l,
        16, 0, 0);
}

// ---------------------------------------------------------------------------
// K0b: pre-split B and C into hi/lo bf16 planes; block 256 computes lam.
// Bsp planes: [re_hi, re_lo, im_hi, im_lo], layout [p][h]
// Csp planes: [re_hi, re_lo, nim_hi, nim_lo] (imag NEGATED), layout [h][p]
// ---------------------------------------------------------------------------
__global__ __launch_bounds__(256) void k0b_prep(const float* __restrict__ Bm,
                                                const float* __restrict__ Cm,
                                                const float* __restrict__ A,
                                                const float* __restrict__ G,
                                                const float* __restrict__ steps,
                                                unsigned short* __restrict__ Bsp,
                                                unsigned short* __restrict__ Csp,
                                                float* __restrict__ lam) {
    if (blockIdx.x == 256) {
        int p = threadIdx.x;
        if (p < SSM) {
            float stp   = 1.f / (1.f + expf(-steps[p]));
            float g     = fmaxf(G[p], 0.f);
            float denom = fmaxf(stp * stp, 1e-6f);
            float s     = stp * g;
            float base  = sqrtf(fmaxf(1.f + s, 1e-6f));
            float alow  = (2.f + s - 2.f * base) / denom;
            float ahigh = (2.f + s + 2.f * base) / denom;
            float a     = alow + fmaxf(A[p] - alow, 0.f) - fmaxf(A[p] - ahigh, 0.f);
            float S     = 1.f / (1.f + stp * g);
            float T     = S + 1.f - stp * stp * S * a;
            lam[p]       = 0.5f * T;
            lam[SSM + p] = sqrtf(fmaxf(S - 0.25f * T * T, 0.f));
        }
        return;
    }
    int gidx = blockIdx.x * 256 + threadIdx.x;
    if (gidx < 32768) {
        int p = gidx >> 7, h = gidx & 127;
        float vr = Bm[(size_t)(p * HID + h) * 2];
        float vi = Bm[(size_t)(p * HID + h) * 2 + 1];
        unsigned short hh = f2bf_hi(vr);
        Bsp[0 * BPL + p * HID + h] = hh;
        Bsp[1 * BPL + p * HID + h] = f2bf(vr - bf2f(hh));
        hh = f2bf_hi(vi);
        Bsp[2 * BPL + p * HID + h] = hh;
        Bsp[3 * BPL + p * HID + h] = f2bf(vi - bf2f(hh));
    } else {
        int g2 = gidx - 32768;
        int h = g2 >> 8, p = g2 & 255;
        float vr = Cm[(size_t)(h * SSM + p) * 2];
        float vi = -Cm[(size_t)(h * SSM + p) * 2 + 1];
        unsigned short hh = f2bf_hi(vr);
        Csp[0 * CPL + h * SSM + p] = hh;
        Csp[1 * CPL + h * SSM + p] = f2bf(vr - bf2f(hh));
        hh = f2bf_hi(vi);
        Csp[2 * CPL + h * SSM + p] = hh;
        Csp[3 * CPL + h * SSM + p] = f2bf(vi - bf2f(hh));
    }
}

// ---------------------------------------------------------------------------
// KU: stream-convert u (f32) -> ubf (bf16 RNE), same [b][l][h] layout.
// ---------------------------------------------------------------------------
__global__ __launch_bounds__(256) void ku_cvt(const float* __restrict__ u,
                                              unsigned short* __restrict__ ubf) {
    const int total = BATCH * LEN * HID;
    const int stride = 2048 * 256 * 8;
    for (int i = (blockIdx.x * 256 + threadIdx.x) * 8; i < total; i += stride) {
        f32x4 a = *(const f32x4*)&u[i];
        f32x4 c = *(const f32x4*)&u[i + 4];
        i32x4 o;
        o[0] = (int)cvtpk(a[0], a[1]);
        o[1] = (int)cvtpk(a[2], a[3]);
        o[2] = (int)cvtpk(c[0], c[1]);
        o[3] = (int)cvtpk(c[2], c[3]);
        *(i32x4*)&ubf[i] = o;
    }
}

// ---------------------------------------------------------------------------
// K12 v8 (pipelined): 512-thread blocks, 16 p-cols x one b, 16 l-tiles.
// Skewed schedule per iter t:
//   STAGE(t+2) | GEMM(t+1) issue (MFMA, results used next iter) | ph2(t)+sT(t)
//   -> barA -> store(t) | ph1(t+1)+Rld -> barB
// GEMM's MFMA+ds_read latency hides under ph2/sT; staged loads drain at barB.
// Buffer/Rld/sT hazards all barrier-separated (see R10 analysis).
// Scan algebra / staging / stores byte-identical to verified R10.
// ---------------------------------------------------------------------------
__global__ __launch_bounds__(512, 4) void k12_fused(const unsigned short* __restrict__ ubf,
                                                    const unsigned short* __restrict__ Bsp,
                                                    const float* __restrict__ lam,
                                                    unsigned short* __restrict__ planes) {
    __shared__ __align__(16) char sU[2][32768];             // dbuf: 128 rows x 256B
    __shared__ __align__(16) unsigned short sT[2][16][136]; // [comp][p16][l(128)+pad]
    __shared__ float Rld[4][2][8][2];                       // [wl][wp][p8][re/im]

    int d    = blockIdx.x;           // 0..511
    int xcd  = d & 7;
    int idx  = d >> 3;               // 0..63
    int pt   = idx & 15;             // 16 p-tiles of 16
    int bhi  = idx >> 4;             // 0..3
    int b    = bhi * 8 + xcd;
    int p0   = pt * 16;

    int tid  = threadIdx.x;
    int lane = tid & 63, w = tid >> 6;
    int wl   = w >> 1, wp = w & 1;
    int fr   = lane & 15, g = lane >> 4;
    int frp  = fr & 7;               // p-column within octet
    int comp = fr >> 3;              // 0 = re, 1 = im
    int pcol = p0 + wp * 8 + frp;    // this lane's p

    // ---- B fragments: lane's comp & p-col, hi/lo x 4 k-chunks ----
    const unsigned short* Bh  = Bsp + (size_t)(comp * 2) * BPL + (size_t)pcol * HID;
    const unsigned short* Blo = Bsp + (size_t)(comp * 2 + 1) * BPL + (size_t)pcol * HID;
    bf16x8 Bfh[4], Bfl[4];
#pragma unroll
    for (int kc = 0; kc < 4; ++kc) {
        Bfh[kc] = *(const bf16x8*)&Bh[kc * 32 + g * 8];
        Bfl[kc] = *(const bf16x8*)&Blo[kc * 32 + g * 8];
    }

    // ---- lambda powers for p = pcol ----
    float pw_r[4], pw_i[4];          // lam^(r+1)
    float lg_r, lg_i;                // lam^(4g)
    float l4r, l4i, l8r, l8i, l16r, l16i, l32r, l32i;
    {
        float ar = lam[pcol], ai = lam[SSM + pcol];
        pw_r[0] = ar; pw_i[0] = ai;
        cmul(pw_r[1], pw_i[1], ar, ai, ar, ai);
        cmul(pw_r[2], pw_i[2], pw_r[1], pw_i[1], ar, ai);
        cmul(pw_r[3], pw_i[3], pw_r[1], pw_i[1], pw_r[1], pw_i[1]);
        l4r = pw_r[3]; l4i = pw_i[3];
        cmul(l8r, l8i, l4r, l4i, l4r, l4i);
        cmul(l16r, l16i, l8r, l8i, l8r, l8i);
        cmul(l32r, l32i, l16r, l16i, l16r, l16i);
        if (g == 0)      { lg_r = 1.f; lg_i = 0.f; }
        else if (g == 1) { lg_r = l4r; lg_i = l4i; }
        else if (g == 2) { lg_r = l8r; lg_i = l8i; }
        else             { cmul(lg_r, lg_i, l8r, l8i, l4r, l4i); }
    }

    float TCr = 0.f, TCi = 0.f;      // running tile carry (per wp group)

    const unsigned short* ub = ubf + (size_t)b * (LEN * HID);
    int srow32  = tid >> 4;          // 0..31
    int stg_src = srow32 * HID + ((((tid & 15) * 16) ^ ((srow32 & 7) << 4)) >> 1);

#define STAGE(buf, tt)                                                        \
    {                                                                         \
        const unsigned short* gs = ub + (size_t)(tt) * 16384 + stg_src;       \
        char* ls = &sU[buf][tid * 16];                                        \
        _Pragma("unroll")                                                     \
        for (int q = 0; q < 4; ++q)                                           \
            gload16(gs + q * 4096, ls + q * 8192);                            \
    }

    f32x4 acc[2];
    float xr[2][4], xi[2][4];
    float Er[2], Ei[2], Fr[2], Fi[2];

    // GEMM: issue 16 MFMAs against sU[bufidx] into acc (results used later)
#define DO_GEMM(bufidx)                                                       \
    {                                                                         \
        const char* su = &sU[bufidx][0];                                      \
        acc[0] = (f32x4)(0.f); acc[1] = (f32x4)(0.f);                         \
        __builtin_amdgcn_s_setprio(1);                                        \
        _Pragma("unroll")                                                     \
        for (int kc = 0; kc < 4; ++kc) {                                      \
            _Pragma("unroll")                                                 \
            for (int mi = 0; mi < 2; ++mi) {                                  \
                int off = (wl * 32 + mi * 16 + fr) * 256 +                    \
                          ((kc * 64 + g * 16) ^ ((fr & 7) << 4));             \
                bf16x8 ah = *(const bf16x8*)(su + off);                       \
                acc[mi] = __builtin_amdgcn_mfma_f32_16x16x32_bf16(ah, Bfh[kc], acc[mi], 0, 0, 0); \
                acc[mi] = __builtin_amdgcn_mfma_f32_16x16x32_bf16(ah, Bfl[kc], acc[mi], 0, 0, 0); \
            }                                                                 \
        }                                                                     \
        __builtin_amdgcn_s_setprio(0);                                        \
    }

    // PH1: consume acc -> xr/xi (local scans), Er/Fi, Rld write
#define DO_PH1()                                                              \
    {                                                                         \
        _Pragma("unroll")                                                     \
        for (int mi = 0; mi < 2; ++mi)                                        \
            _Pragma("unroll")                                                 \
            for (int e = 0; e < 4; ++e) {                                     \
                float other = __shfl_xor(acc[mi][e], 8, 64);                  \
                xr[mi][e] = (comp == 0) ? acc[mi][e] : other;                 \
                xi[mi][e] = (comp == 0) ? other      : acc[mi][e];            \
            }                                                                 \
        float lr = pw_r[0], li = pw_i[0];                                     \
        float Qr[2], Qi[2];                                                   \
        _Pragma("unroll")                                                     \
        for (int mi = 0; mi < 2; ++mi) {                                      \
            float cr = 0.f, ci = 0.f;                                         \
            _Pragma("unroll")                                                 \
            for (int r = 0; r < 4; ++r) {                                     \
                float nr = fmaf(lr, cr, fmaf(-li, ci, xr[mi][r]));            \
                float ni = fmaf(lr, ci, fmaf(li, cr, xi[mi][r]));             \
                cr = nr; ci = ni;                                             \
                xr[mi][r] = cr; xi[mi][r] = ci;                               \
            }                                                                 \
            Qr[mi] = cr; Qi[mi] = ci;                                         \
        }                                                                     \
        _Pragma("unroll")                                                     \
        for (int mi = 0; mi < 2; ++mi) {                                      \
            float ur = __shfl_up(Qr[mi], 16u, 64);                            \
            float ui = __shfl_up(Qi[mi], 16u, 64);                            \
            if (g >= 1) {                                                     \
                Qr[mi] = fmaf(l4r, ur, fmaf(-l4i, ui, Qr[mi]));               \
                Qi[mi] = fmaf(l4r, ui, fmaf(l4i, ur, Qi[mi]));                \
            }                                                                 \
            ur = __shfl_up(Qr[mi], 32u, 64);                                  \
            ui = __shfl_up(Qi[mi], 32u, 64);                                  \
            if (g >= 2) {                                                     \
                Qr[mi] = fmaf(l8r, ur, fmaf(-l8i, ui, Qr[mi]));               \
                Qi[mi] = fmaf(l8r, ui, fmaf(l8i, ur, Qi[mi]));                \
            }                                                                 \
            float er = __shfl_up(Qr[mi], 16u, 64);                            \
            float ei = __shfl_up(Qi[mi], 16u, 64);                            \
            if (g == 0) { er = 0.f; ei = 0.f; }                               \
            Er[mi] = er; Ei[mi] = ei;                                         \
            Fr[mi] = __shfl(Qr[mi], fr + 48, 64);                             \
            Fi[mi] = __shfl(Qi[mi], fr + 48, 64);                             \
        }                                                                     \
        float Rr = fmaf(l16r, Fr[0], fmaf(-l16i, Fi[0], Fr[1]));              \
        float Ri = fmaf(l16r, Fi[0], fmaf(l16i, Fr[0], Fi[1]));               \
        if (g == 0 && fr < 8) { Rld[wl][wp][fr][0] = Rr; Rld[wl][wp][fr][1] = Ri; } \
    }

    // ---- prologue ----
    STAGE(0, 0)
    __syncthreads();                 // drain tile 0
    STAGE(1, 1)                      // tile 1 in flight
    DO_GEMM(0)                       // tile 0
    DO_PH1()                         // tile 0 local scans + Rld(0)
    __syncthreads();                 // barB(-1): Rld(0) ready; STAGE(1) drained

    for (int t = 0; t < 16; ++t) {
        int l0t = t * 128;

        if (t < 14) STAGE(t & 1, t + 2)       // retired buffer; safe per barB(t-1)
        if (t < 15) DO_GEMM((t + 1) & 1)      // MFMA issue; consumed at ph1 below

        // ---- ph2(t): cross-wave lam^32 chain, corrections ----
        {
            float Wr = TCr, Wi = TCi;
            float Tr = TCr, Ti = TCi;
#pragma unroll
            for (int w2 = 0; w2 < 4; ++w2) {
                float rr = Rld[w2][wp][frp][0], ri = Rld[w2][wp][frp][1];
                float nTr = fmaf(l32r, Tr, fmaf(-l32i, Ti, rr));
                float nTi = fmaf(l32r, Ti, fmaf(l32i, Tr, ri));
                Tr = nTr; Ti = nTi;
                if (w2 < wl) {
                    float nWr = fmaf(l32r, Wr, fmaf(-l32i, Wi, rr));
                    float nWi = fmaf(l32r, Wi, fmaf(l32i, Wr, ri));
                    Wr = nWr; Wi = nWi;
                }
            }
            TCr = Tr; TCi = Ti;
            float p1r = fmaf(l16r, Wr, fmaf(-l16i, Wi, Fr[0]));
            float p1i = fmaf(l16r, Wi, fmaf(l16i, Wr, Fi[0]));
#pragma unroll
            for (int mi = 0; mi < 2; ++mi) {
                float prr = (mi == 0) ? Wr : p1r;
                float pri = (mi == 0) ? Wi : p1i;
                float Mr = fmaf(lg_r, prr, fmaf(-lg_i, pri, Er[mi]));
                float Mi = fmaf(lg_r, pri, fmaf(lg_i, prr, Ei[mi]));
#pragma unroll
                for (int r = 0; r < 4; ++r) {
                    xr[mi][r] = fmaf(pw_r[r], Mr, fmaf(-pw_i[r], Mi, xr[mi][r]));
                    xi[mi][r] = fmaf(pw_r[r], Mi, fmaf(pw_i[r], Mr, xi[mi][r]));
                }
            }
        }

        // ---- stage bf16 states into sT (lane writes its comp only) ----
#pragma unroll
        for (int mi = 0; mi < 2; ++mi) {
            int col = wl * 32 + mi * 16 + g * 4;
            u32x2 pk;
            if (comp == 0) {
                pk.x = cvtpk(xr[mi][0], xr[mi][1]);
                pk.y = cvtpk(xr[mi][2], xr[mi][3]);
            } else {
                pk.x = cvtpk(xi[mi][0], xi[mi][1]);
                pk.y = cvtpk(xi[mi][2], xi[mi][3]);
            }
            *(u32x2*)&sT[comp][wp * 8 + frp][col] = pk;
        }
        __syncthreads();   // barA: sT(t) ready

        // ---- coalesced stores: 32 rows x 256B (16 threads x 16B each) ----
        {
            int rowid = tid >> 4;          // 0..31
            int pl = rowid >> 4, pp = rowid & 15;
            int c8 = (tid & 15) * 8;
            bf16x8 v = *(const bf16x8*)&sT[pl][pp][c8];
            *(bf16x8*)&planes[(size_t)pl * PLz +
                    ((size_t)(b * SSM + p0 + pp)) * LEN + l0t + c8] = v;
        }

        if (t < 15) DO_PH1()               // tile t+1 local scans + Rld(t+1)
        __syncthreads();   // barB: Rld(t+1) ready; sT reads done; staging drained
    }
#undef STAGE
#undef DO_GEMM
#undef DO_PH1
}

// ---------------------------------------------------------------------------
// K3 (MFMA): out[b][l][h] = sum_p s_re*C_re - s_im*C_im + u*D  (verified R10)
// ---------------------------------------------------------------------------
__global__ __launch_bounds__(256) void k3_out(const unsigned short* __restrict__ planes,
                                              const unsigned short* __restrict__ Csp,
                                              const unsigned short* __restrict__ ubf,
                                              const float* __restrict__ D,
                                              float* __restrict__ out) {
    __shared__ __align__(16) unsigned short sA[2][128][40];
    __shared__ __align__(16) unsigned short sC[4][128][40];
    int d   = blockIdx.x;           // 0..511
    int xcd = d & 7;
    int grp = d >> 3;               // 0..63
    int lt  = grp & 15;
    int bhi = grp >> 4;             // 0..3
    int b   = bhi * 8 + xcd;
    int l0  = lt * 128;

    int tid = threadIdx.x;
    int lane = tid & 63, w = tid >> 6;
    int wl = w >> 1, wh = w & 1;
    int fr = lane & 15, g = lane >> 4;

    f32x4 acc[4][4];
#pragma unroll
    for (int mi = 0; mi < 4; ++mi)
#pragma unroll
        for (int ni = 0; ni < 4; ++ni) acc[mi][ni] = (f32x4)(0.f);

    float dv[4];
#pragma unroll
    for (int ni = 0; ni < 4; ++ni) dv[ni] = D[wh * 64 + ni * 16 + fr];

    for (int pc = 0; pc < SSM; pc += 32) {
        {
            int loct = tid & 15;
#pragma unroll
            for (int r = 0; r < 2; ++r) {
                int p_ = (tid >> 4) + 16 * r;
                int rot = (loct + p_) & 7;
#pragma unroll
                for (int pl = 0; pl < 2; ++pl) {
                    union { bf16x8 v; unsigned long long q[2]; } U;
                    U.v = *(const bf16x8*)&planes[(size_t)pl * PLz +
                            ((size_t)(b * SSM + pc + p_)) * LEN + l0 + loct * 8];
                    unsigned long long x0 = U.q[0], x1 = U.q[1];
                    if (rot & 4) { unsigned long long tq = x0; x0 = x1; x1 = tq; }
                    if (rot & 2) {
                        unsigned long long n0 = (x0 >> 32) | (x1 << 32);
                        unsigned long long n1 = (x1 >> 32) | (x0 << 32);
                        x0 = n0; x1 = n1;
                    }
                    if (rot & 1) {
                        unsigned long long n0 = (x0 >> 16) | (x1 << 48);
                        unsigned long long n1 = (x1 >> 16) | (x0 << 48);
                        x0 = n0; x1 = n1;
                    }
                    int rb = loct * 8;
                    sA[pl][rb + ((0 + rot) & 7)][p_] = (unsigned short)(x0);
                    sA[pl][rb + ((1 + rot) & 7)][p_] = (unsigned short)(x0 >> 16);
                    sA[pl][rb + ((2 + rot) & 7)][p_] = (unsigned short)(x0 >> 32);
                    sA[pl][rb + ((3 + rot) & 7)][p_] = (unsigned short)(x0 >> 48);
                    sA[pl][rb + ((4 + rot) & 7)][p_] = (unsigned short)(x1);
                    sA[pl][rb + ((5 + rot) & 7)][p_] = (unsigned short)(x1 >> 16);
                    sA[pl][rb + ((6 + rot) & 7)][p_] = (unsigned short)(x1 >> 32);
                    sA[pl][rb + ((7 + rot) & 7)][p_] = (unsigned short)(x1 >> 48);
                }
            }
        }
        {
            int poct = tid & 3;
#pragma unroll
            for (int r2 = 0; r2 < 2; ++r2) {
                int hh = (tid >> 2) + 64 * r2;
#pragma unroll
                for (int pl = 0; pl < 4; ++pl) {
                    i32x4 v = *(const i32x4*)&Csp[(size_t)pl * CPL + (size_t)hh * SSM + pc + poct * 8];
                    *(i32x4*)&sC[pl][hh][poct * 8] = v;
                }
            }
        }
        __syncthreads();

        int kk = g * 8;
        bf16x8 crh[4], crl[4], cih[4], cil[4];
#pragma unroll
        for (int ni = 0; ni < 4; ++ni) {
            int hr = wh * 64 + ni * 16 + fr;
            crh[ni] = *(const bf16x8*)&sC[0][hr][kk];
            crl[ni] = *(const bf16x8*)&sC[1][hr][kk];
            cih[ni] = *(const bf16x8*)&sC[2][hr][kk];
            cil[ni] = *(const bf16x8*)&sC[3][hr][kk];
        }
#pragma unroll
        for (int mi = 0; mi < 4; ++mi) {
            int lr_ = wl * 64 + mi * 16 + fr;
            bf16x8 ar = *(const bf16x8*)&sA[0][lr_][kk];
            bf16x8 ai = *(const bf16x8*)&sA[1][lr_][kk];
#pragma unroll
            for (int ni = 0; ni < 4; ++ni) {
                acc[mi][ni] = __builtin_amdgcn_mfma_f32_16x16x32_bf16(ar, crh[ni], acc[mi][ni], 0, 0, 0);
                acc[mi][ni] = __builtin_amdgcn_mfma_f32_16x16x32_bf16(ar, crl[ni], acc[mi][ni], 0, 0, 0);
                acc[mi][ni] = __builtin_amdgcn_mfma_f32_16x16x32_bf16(ai, cih[ni], acc[mi][ni], 0, 0, 0);
                acc[mi][ni] = __builtin_amdgcn_mfma_f32_16x16x32_bf16(ai, cil[ni], acc[mi][ni], 0, 0, 0);
            }
        }
        __syncthreads();
    }

#pragma unroll
    for (int mi = 0; mi < 4; ++mi)
#pragma unroll
        for (int ni = 0; ni < 4; ++ni) {
            int lb = l0 + wl * 64 + mi * 16 + g * 4;
            int h = wh * 64 + ni * 16 + fr;
#pragma unroll
            for (int r = 0; r < 4; ++r) {
                size_t idx = ((size_t)b * LEN + lb + r) * HID + h;
                out[idx] = acc[mi][ni][r] + bf2f(ubf[idx]) * dv[ni];
            }
        }
}

// ---------------------------------------------------------------------------
// Workspace layout (bytes):
//   [0, 67108864)              2 bf16 state planes [re, im]
//   [67108864, 67110912)       lam (512 f32)
//   [67110912, 67373056)       B split planes (4 x 32768 ushort)
//   [67373056, 67635200)       C split planes (4 x 32768 ushort)
//   [67635200, 84412416)       ubf: u as bf16 [b][l][h]
// ---------------------------------------------------------------------------
extern "C" void kernel_launch(void* const* d_in, const int* in_sizes, int n_in,
                              void* d_out, int out_size, void* d_ws, size_t ws_size,
                              hipStream_t stream) {
    const float* u  = (const float*)d_in[0];
    const float* A  = (const float*)d_in[1];
    const float* G  = (const float*)d_in[2];
    const float* st = (const float*)d_in[3];
    const float* B  = (const float*)d_in[4];
    const float* C  = (const float*)d_in[5];
    const float* D  = (const float*)d_in[6];
    float* out = (float*)d_out;

    char* WS = (char*)d_ws;
    unsigned short* planes = (unsigned short*)WS;
    float* lam             = (float*)(WS + 67108864);
    unsigned short* Bsp    = (unsigned short*)(WS + 67110912);
    unsigned short* Csp    = (unsigned short*)(WS + 67373056);
    unsigned short* ubf    = (unsigned short*)(WS + 67635200);

    k0b_prep<<<257, 256, 0, stream>>>(B, C, A, G, st, Bsp, Csp, lam);
    ku_cvt<<<2048, 256, 0, stream>>>(u, ubf);
    k12_fused<<<512, 512, 0, stream>>>(ubf, Bsp, lam, planes);
    k3_out<<<512, 256, 0, stream>>>(planes, Csp, ubf, D, out);
}

// Round 12
// 90.690 us; speedup vs baseline: 1.2327x; 1.2327x over previous
//
#include <hip/hip_runtime.h>
#include <hip/hip_bf16.h>
#include <math.h>

#define BATCH 32
#define LEN   2048
#define HID   128
#define SSM   256

static const size_t PLz = 16777216;   // elements per state plane (32*256*2048)
#define BPL 32768                     // elements per B-split plane (256*128)
#define CPL 32768                     // elements per C-split plane (128*256)

typedef __attribute__((ext_vector_type(4))) float f32x4;
typedef __attribute__((ext_vector_type(8))) short bf16x8;
typedef __attribute__((ext_vector_type(4))) short bf16x4;
typedef __attribute__((ext_vector_type(4))) int   i32x4;
typedef __attribute__((ext_vector_type(2))) unsigned int u32x2;

// RNE f32->bf16 (bit trick)
static __device__ __forceinline__ unsigned short f2bf(float x) {
    union { float f; unsigned u; } v; v.f = x;
    unsigned r = (v.u + 0x7FFFu + ((v.u >> 16) & 1u)) >> 16;
    return (unsigned short)r;
}
// truncating f32->bf16 (hi term of split; lo captures remainder exactly)
static __device__ __forceinline__ unsigned short f2bf_hi(float x) {
    union { float f; unsigned u; } v; v.f = x;
    return (unsigned short)(v.u >> 16);
}
static __device__ __forceinline__ float bf2f(unsigned short b) {
    union { unsigned u; float f; } v; v.u = ((unsigned)b) << 16;
    return v.f;
}
// packed RNE pair convert -> one u32 (v_cvt_pk_bf16_f32)
static __device__ __forceinline__ unsigned int cvtpk(float a, float b) {
    __hip_bfloat162 h = __float22bfloat162_rn(float2{a, b});
    union { __hip_bfloat162 h2; unsigned int u; } c; c.h2 = h;
    return c.u;
}
static __device__ __forceinline__ void cmul(float& rr, float& ri,
                                            float ar, float ai, float br, float bi) {
    rr = ar * br - ai * bi;
    ri = ar * bi + ai * br;
}
// async global->LDS 16B (zero VGPR round-trip; vmcnt-counted)
static __device__ __forceinline__ void gload16(const void* g, void* l) {
    __builtin_amdgcn_global_load_lds(
        (const __attribute__((address_space(1))) unsigned int*)g,
        (__attribute__((address_space(3))) unsigned int*)l,
        16, 0, 0);
}

// ---------------------------------------------------------------------------
// K0b: pre-split B and C into hi/lo bf16 planes; block 256 computes lam.
// Bsp planes: [re_hi, re_lo, im_hi, im_lo], layout [p][h]
// Csp planes: [re_hi, re_lo, nim_hi, nim_lo] (imag NEGATED), layout [h][p]
// ---------------------------------------------------------------------------
__global__ __launch_bounds__(256) void k0b_prep(const float* __restrict__ Bm,
                                                const float* __restrict__ Cm,
                                                const float* __restrict__ A,
                                                const float* __restrict__ G,
                                                const float* __restrict__ steps,
                                                unsigned short* __restrict__ Bsp,
                                                unsigned short* __restrict__ Csp,
                                                float* __restrict__ lam) {
    if (blockIdx.x == 256) {
        int p = threadIdx.x;
        if (p < SSM) {
            float stp   = 1.f / (1.f + expf(-steps[p]));
            float g     = fmaxf(G[p], 0.f);
            float denom = fmaxf(stp * stp, 1e-6f);
            float s     = stp * g;
            float base  = sqrtf(fmaxf(1.f + s, 1e-6f));
            float alow  = (2.f + s - 2.f * base) / denom;
            float ahigh = (2.f + s + 2.f * base) / denom;
            float a     = alow + fmaxf(A[p] - alow, 0.f) - fmaxf(A[p] - ahigh, 0.f);
            float S     = 1.f / (1.f + stp * g);
            float T     = S + 1.f - stp * stp * S * a;
            lam[p]       = 0.5f * T;
            lam[SSM + p] = sqrtf(fmaxf(S - 0.25f * T * T, 0.f));
        }
        return;
    }
    int gidx = blockIdx.x * 256 + threadIdx.x;
    if (gidx < 32768) {
        int p = gidx >> 7, h = gidx & 127;
        float vr = Bm[(size_t)(p * HID + h) * 2];
        float vi = Bm[(size_t)(p * HID + h) * 2 + 1];
        unsigned short hh = f2bf_hi(vr);
        Bsp[0 * BPL + p * HID + h] = hh;
        Bsp[1 * BPL + p * HID + h] = f2bf(vr - bf2f(hh));
        hh = f2bf_hi(vi);
        Bsp[2 * BPL + p * HID + h] = hh;
        Bsp[3 * BPL + p * HID + h] = f2bf(vi - bf2f(hh));
    } else {
        int g2 = gidx - 32768;
        int h = g2 >> 8, p = g2 & 255;
        float vr = Cm[(size_t)(h * SSM + p) * 2];
        float vi = -Cm[(size_t)(h * SSM + p) * 2 + 1];
        unsigned short hh = f2bf_hi(vr);
        Csp[0 * CPL + h * SSM + p] = hh;
        Csp[1 * CPL + h * SSM + p] = f2bf(vr - bf2f(hh));
        hh = f2bf_hi(vi);
        Csp[2 * CPL + h * SSM + p] = hh;
        Csp[3 * CPL + h * SSM + p] = f2bf(vi - bf2f(hh));
    }
}

// ---------------------------------------------------------------------------
// KU: stream-convert u (f32) -> ubf (bf16 RNE), same [b][l][h] layout.
// ---------------------------------------------------------------------------
__global__ __launch_bounds__(256) void ku_cvt(const float* __restrict__ u,
                                              unsigned short* __restrict__ ubf) {
    const int total = BATCH * LEN * HID;
    const int stride = 2048 * 256 * 8;
    for (int i = (blockIdx.x * 256 + threadIdx.x) * 8; i < total; i += stride) {
        f32x4 a = *(const f32x4*)&u[i];
        f32x4 c = *(const f32x4*)&u[i + 4];
        i32x4 o;
        o[0] = (int)cvtpk(a[0], a[1]);
        o[1] = (int)cvtpk(a[2], a[3]);
        o[2] = (int)cvtpk(c[0], c[1]);
        o[3] = (int)cvtpk(c[2], c[3]);
        *(i32x4*)&ubf[i] = o;
    }
}

// ---------------------------------------------------------------------------
// K12 v9: R10 skeleton (verified 57.6us) + SPLIT SCAN: after the xor-8 swap,
// half A (fr<8) scans the mi=0 fragment, half B (fr>=8) scans mi=1 —
// removing the 2x redundancy of R10's ph1 (both halves computed identical
// scans). One extra shfl_xor(8) exchanges F0 for the wave carry / p1.
// Bit-identical arithmetic per output value. 64-VGPR envelope respected
// (live state DECREASES vs R10 — no spills, unlike R11's skew).
// ---------------------------------------------------------------------------
__global__ __launch_bounds__(512, 4) void k12_fused(const unsigned short* __restrict__ ubf,
                                                    const unsigned short* __restrict__ Bsp,
                                                    const float* __restrict__ lam,
                                                    unsigned short* __restrict__ planes) {
    __shared__ __align__(16) char sU[2][32768];             // dbuf: 128 rows x 256B
    __shared__ __align__(16) unsigned short sT[2][16][136]; // [comp][p16][l(128)+pad]
    __shared__ float Rld[4][2][8][2];                       // [wl][wp][p8][re/im]

    int d    = blockIdx.x;           // 0..511
    int xcd  = d & 7;
    int idx  = d >> 3;               // 0..63
    int pt   = idx & 15;             // 16 p-tiles of 16
    int bhi  = idx >> 4;             // 0..3
    int b    = bhi * 8 + xcd;
    int p0   = pt * 16;

    int tid  = threadIdx.x;
    int lane = tid & 63, w = tid >> 6;
    int wl   = w >> 1, wp = w & 1;
    int fr   = lane & 15, g = lane >> 4;
    int frp  = fr & 7;               // p-column within octet
    int comp = fr >> 3;              // 0 = re-half (owns mi=0), 1 = im-half (owns mi=1)
    int pcol = p0 + wp * 8 + frp;    // this lane's p

    // ---- B fragments: lane's comp & p-col, hi/lo x 4 k-chunks ----
    const unsigned short* Bh  = Bsp + (size_t)(comp * 2) * BPL + (size_t)pcol * HID;
    const unsigned short* Blo = Bsp + (size_t)(comp * 2 + 1) * BPL + (size_t)pcol * HID;
    bf16x8 Bfh[4], Bfl[4];
#pragma unroll
    for (int kc = 0; kc < 4; ++kc) {
        Bfh[kc] = *(const bf16x8*)&Bh[kc * 32 + g * 8];
        Bfl[kc] = *(const bf16x8*)&Blo[kc * 32 + g * 8];
    }

    // ---- lambda powers for p = pcol ----
    float pw_r[4], pw_i[4];          // lam^(r+1)
    float lg_r, lg_i;                // lam^(4g)
    float l4r, l4i, l8r, l8i, l16r, l16i, l32r, l32i;
    {
        float ar = lam[pcol], ai = lam[SSM + pcol];
        pw_r[0] = ar; pw_i[0] = ai;
        cmul(pw_r[1], pw_i[1], ar, ai, ar, ai);
        cmul(pw_r[2], pw_i[2], pw_r[1], pw_i[1], ar, ai);
        cmul(pw_r[3], pw_i[3], pw_r[1], pw_i[1], pw_r[1], pw_i[1]);
        l4r = pw_r[3]; l4i = pw_i[3];
        cmul(l8r, l8i, l4r, l4i, l4r, l4i);
        cmul(l16r, l16i, l8r, l8i, l8r, l8i);
        cmul(l32r, l32i, l16r, l16i, l16r, l16i);
        if (g == 0)      { lg_r = 1.f; lg_i = 0.f; }
        else if (g == 1) { lg_r = l4r; lg_i = l4i; }
        else if (g == 2) { lg_r = l8r; lg_i = l8i; }
        else             { cmul(lg_r, lg_i, l8r, l8i, l4r, l4i); }
    }

    float TCr = 0.f, TCi = 0.f;      // running tile carry (per wp group)

    const unsigned short* ub = ubf + (size_t)b * (LEN * HID);
    int srow32  = tid >> 4;          // 0..31
    int stg_src = srow32 * HID + ((((tid & 15) * 16) ^ ((srow32 & 7) << 4)) >> 1);

#define STAGE(buf, tt)                                                        \
    {                                                                         \
        const unsigned short* gs = ub + (size_t)(tt) * 16384 + stg_src;       \
        char* ls = &sU[buf][tid * 16];                                        \
        _Pragma("unroll")                                                     \
        for (int q = 0; q < 4; ++q)                                           \
            gload16(gs + q * 4096, ls + q * 8192);                            \
    }

    // ---- prologue: stage tile 0, drain ----
    STAGE(0, 0)
    __syncthreads();
    int cur = 0;

    for (int t = 0; t < 16; ++t) {
        int l0t = t * 128;

        // ---- issue next tile's async staging (hidden under GEMM+scan) ----
        if (t < 15) STAGE(cur ^ 1, t + 1)

        // ---- GEMM: wave rows wl*32..wl*32+31; B packs [re|im] ----
        const char* su = &sU[cur][0];
        f32x4 acc[2];
        acc[0] = (f32x4)(0.f); acc[1] = (f32x4)(0.f);
#pragma unroll
        for (int kc = 0; kc < 4; ++kc) {
#pragma unroll
            for (int mi = 0; mi < 2; ++mi) {
                int off = (wl * 32 + mi * 16 + fr) * 256 + ((kc * 64 + g * 16) ^ ((fr & 7) << 4));
                bf16x8 ah = *(const bf16x8*)(su + off);
                acc[mi] = __builtin_amdgcn_mfma_f32_16x16x32_bf16(ah, Bfh[kc], acc[mi], 0, 0, 0);
                acc[mi] = __builtin_amdgcn_mfma_f32_16x16x32_bf16(ah, Bfl[kc], acc[mi], 0, 0, 0);
            }
        }

        // ---- split swap: each lane keeps ONLY its own mi (= comp) ----
        // partner needs acc[comp^1]; send that, receive our missing half.
        float xr[4], xi[4];
#pragma unroll
        for (int e = 0; e < 4; ++e) {
            float send = (comp == 0) ? acc[1][e] : acc[0][e];
            float oth  = __shfl_xor(send, 8, 64);
            xr[e] = (comp == 0) ? acc[0][e] : oth;
            xi[e] = (comp == 0) ? oth       : acc[1][e];
        }

        // ---- scan phase 1 (split): quad scan + g-scan on own fragment ----
        float Er, Ei, Fr, Fi, For, Foi;
        {
            float lr = pw_r[0], li = pw_i[0];
            float cr = 0.f, ci = 0.f;
#pragma unroll
            for (int r = 0; r < 4; ++r) {
                float nr = fmaf(lr, cr, fmaf(-li, ci, xr[r]));
                float ni = fmaf(lr, ci, fmaf(li, cr, xi[r]));
                cr = nr; ci = ni;
                xr[r] = cr; xi[r] = ci;
            }
            float Qr = cr, Qi = ci;
            float ur = __shfl_up(Qr, 16u, 64);
            float ui = __shfl_up(Qi, 16u, 64);
            if (g >= 1) {
                Qr = fmaf(l4r, ur, fmaf(-l4i, ui, Qr));
                Qi = fmaf(l4r, ui, fmaf(l4i, ur, Qi));
            }
            ur = __shfl_up(Qr, 32u, 64);
            ui = __shfl_up(Qi, 32u, 64);
            if (g >= 2) {
                Qr = fmaf(l8r, ur, fmaf(-l8i, ui, Qr));
                Qi = fmaf(l8r, ui, fmaf(l8i, ur, Qi));
            }
            Er = __shfl_up(Qr, 16u, 64);
            Ei = __shfl_up(Qi, 16u, 64);
            if (g == 0) { Er = 0.f; Ei = 0.f; }
            Fr = __shfl(Qr, fr + 48, 64);   // own-frag total carry
            Fi = __shfl(Qi, fr + 48, 64);
            For = __shfl_xor(Fr, 8, 64);    // partner-frag carry (halfB gets F0)
            Foi = __shfl_xor(Fi, 8, 64);
            // wave carry R = F1 + lam^16 * F0  (half B holds F1, For=F0)
            float Rr = fmaf(l16r, For, fmaf(-l16i, Foi, Fr));
            float Ri = fmaf(l16r, Foi, fmaf(l16i, For, Fi));
            if (g == 0 && fr >= 8) { Rld[wl][wp][frp][0] = Rr; Rld[wl][wp][frp][1] = Ri; }
        }
        __syncthreads();   // bar2: Rld ready; sU[cur] reads done; staging drained

        // ---- scan phase 2: cross-wave lam^32 chain; own-mi corrections ----
        {
            float Wr = TCr, Wi = TCi;
            float Tr = TCr, Ti = TCi;
#pragma unroll
            for (int w2 = 0; w2 < 4; ++w2) {
                float rr = Rld[w2][wp][frp][0], ri = Rld[w2][wp][frp][1];
                float nTr = fmaf(l32r, Tr, fmaf(-l32i, Ti, rr));
                float nTi = fmaf(l32r, Ti, fmaf(l32i, Tr, ri));
                Tr = nTr; Ti = nTi;
                if (w2 < wl) {
                    float nWr = fmaf(l32r, Wr, fmaf(-l32i, Wi, rr));
                    float nWi = fmaf(l32r, Wi, fmaf(l32i, Wr, ri));
                    Wr = nWr; Wi = nWi;
                }
            }
            TCr = Tr; TCi = Ti;
            // pre: half A (mi=0) -> W ; half B (mi=1) -> lam^16*W + F0 (=For)
            float prr, pri;
            if (comp == 0) { prr = Wr; pri = Wi; }
            else {
                prr = fmaf(l16r, Wr, fmaf(-l16i, Wi, For));
                pri = fmaf(l16r, Wi, fmaf(l16i, Wr, Foi));
            }
            float Mr = fmaf(lg_r, prr, fmaf(-lg_i, pri, Er));
            float Mi = fmaf(lg_r, pri, fmaf(lg_i, prr, Ei));
#pragma unroll
            for (int r = 0; r < 4; ++r) {
                xr[r] = fmaf(pw_r[r], Mr, fmaf(-pw_i[r], Mi, xr[r]));
                xi[r] = fmaf(pw_r[r], Mi, fmaf(pw_i[r], Mr, xi[r]));
            }
        }

        // ---- stage bf16 states into sT: each lane writes BOTH comps of
        //      its own mi (= comp) fragment ----
        {
            int col = wl * 32 + comp * 16 + g * 4;
            u32x2 pk0, pk1;
            pk0.x = cvtpk(xr[0], xr[1]); pk0.y = cvtpk(xr[2], xr[3]);
            pk1.x = cvtpk(xi[0], xi[1]); pk1.y = cvtpk(xi[2], xi[3]);
            *(u32x2*)&sT[0][wp * 8 + frp][col] = pk0;
            *(u32x2*)&sT[1][wp * 8 + frp][col] = pk1;
        }
        __syncthreads();   // bar3: sT ready

        // ---- coalesced stores: 32 rows x 256B (16 threads x 16B each) ----
        {
            int rowid = tid >> 4;          // 0..31
            int pl = rowid >> 4, pp = rowid & 15;
            int c8 = (tid & 15) * 8;
            bf16x8 v = *(const bf16x8*)&sT[pl][pp][c8];
            *(bf16x8*)&planes[(size_t)pl * PLz +
                    ((size_t)(b * SSM + p0 + pp)) * LEN + l0t + c8] = v;
        }
        cur ^= 1;
        // sT rewrite is gated by the NEXT bar2, which follows all sT reads.
    }
#undef STAGE
}

// ---------------------------------------------------------------------------
// K3 (MFMA): out[b][l][h] = sum_p s_re*C_re - s_im*C_im + u*D  (verified)
// ---------------------------------------------------------------------------
__global__ __launch_bounds__(256) void k3_out(const unsigned short* __restrict__ planes,
                                              const unsigned short* __restrict__ Csp,
                                              const unsigned short* __restrict__ ubf,
                                              const float* __restrict__ D,
                                              float* __restrict__ out) {
    __shared__ __align__(16) unsigned short sA[2][128][40];
    __shared__ __align__(16) unsigned short sC[4][128][40];
    int d   = blockIdx.x;           // 0..511
    int xcd = d & 7;
    int grp = d >> 3;               // 0..63
    int lt  = grp & 15;
    int bhi = grp >> 4;             // 0..3
    int b   = bhi * 8 + xcd;
    int l0  = lt * 128;

    int tid = threadIdx.x;
    int lane = tid & 63, w = tid >> 6;
    int wl = w >> 1, wh = w & 1;
    int fr = lane & 15, g = lane >> 4;

    f32x4 acc[4][4];
#pragma unroll
    for (int mi = 0; mi < 4; ++mi)
#pragma unroll
        for (int ni = 0; ni < 4; ++ni) acc[mi][ni] = (f32x4)(0.f);

    float dv[4];
#pragma unroll
    for (int ni = 0; ni < 4; ++ni) dv[ni] = D[wh * 64 + ni * 16 + fr];

    for (int pc = 0; pc < SSM; pc += 32) {
        {
            int loct = tid & 15;
#pragma unroll
            for (int r = 0; r < 2; ++r) {
                int p_ = (tid >> 4) + 16 * r;
                int rot = (loct + p_) & 7;
#pragma unroll
                for (int pl = 0; pl < 2; ++pl) {
                    union { bf16x8 v; unsigned long long q[2]; } U;
                    U.v = *(const bf16x8*)&planes[(size_t)pl * PLz +
                            ((size_t)(b * SSM + pc + p_)) * LEN + l0 + loct * 8];
                    unsigned long long x0 = U.q[0], x1 = U.q[1];
                    if (rot & 4) { unsigned long long tq = x0; x0 = x1; x1 = tq; }
                    if (rot & 2) {
                        unsigned long long n0 = (x0 >> 32) | (x1 << 32);
                        unsigned long long n1 = (x1 >> 32) | (x0 << 32);
                        x0 = n0; x1 = n1;
                    }
                    if (rot & 1) {
                        unsigned long long n0 = (x0 >> 16) | (x1 << 48);
                        unsigned long long n1 = (x1 >> 16) | (x0 << 48);
                        x0 = n0; x1 = n1;
                    }
                    int rb = loct * 8;
                    sA[pl][rb + ((0 + rot) & 7)][p_] = (unsigned short)(x0);
                    sA[pl][rb + ((1 + rot) & 7)][p_] = (unsigned short)(x0 >> 16);
                    sA[pl][rb + ((2 + rot) & 7)][p_] = (unsigned short)(x0 >> 32);
                    sA[pl][rb + ((3 + rot) & 7)][p_] = (unsigned short)(x0 >> 48);
                    sA[pl][rb + ((4 + rot) & 7)][p_] = (unsigned short)(x1);
                    sA[pl][rb + ((5 + rot) & 7)][p_] = (unsigned short)(x1 >> 16);
                    sA[pl][rb + ((6 + rot) & 7)][p_] = (unsigned short)(x1 >> 32);
                    sA[pl][rb + ((7 + rot) & 7)][p_] = (unsigned short)(x1 >> 48);
                }
            }
        }
        {
            int poct = tid & 3;
#pragma unroll
            for (int r2 = 0; r2 < 2; ++r2) {
                int hh = (tid >> 2) + 64 * r2;
#pragma unroll
                for (int pl = 0; pl < 4; ++pl) {
                    i32x4 v = *(const i32x4*)&Csp[(size_t)pl * CPL + (size_t)hh * SSM + pc + poct * 8];
                    *(i32x4*)&sC[pl][hh][poct * 8] = v;
                }
            }
        }
        __syncthreads();

        int kk = g * 8;
        bf16x8 crh[4], crl[4], cih[4], cil[4];
#pragma unroll
        for (int ni = 0; ni < 4; ++ni) {
            int hr = wh * 64 + ni * 16 + fr;
            crh[ni] = *(const bf16x8*)&sC[0][hr][kk];
            crl[ni] = *(const bf16x8*)&sC[1][hr][kk];
            cih[ni] = *(const bf16x8*)&sC[2][hr][kk];
            cil[ni] = *(const bf16x8*)&sC[3][hr][kk];
        }
#pragma unroll
        for (int mi = 0; mi < 4; ++mi) {
            int lr_ = wl * 64 + mi * 16 + fr;
            bf16x8 ar = *(const bf16x8*)&sA[0][lr_][kk];
            bf16x8 ai = *(const bf16x8*)&sA[1][lr_][kk];
#pragma unroll
            for (int ni = 0; ni < 4; ++ni) {
                acc[mi][ni] = __builtin_amdgcn_mfma_f32_16x16x32_bf16(ar, crh[ni], acc[mi][ni], 0, 0, 0);
                acc[mi][ni] = __builtin_amdgcn_mfma_f32_16x16x32_bf16(ar, crl[ni], acc[mi][ni], 0, 0, 0);
                acc[mi][ni] = __builtin_amdgcn_mfma_f32_16x16x32_bf16(ai, cih[ni], acc[mi][ni], 0, 0, 0);
                acc[mi][ni] = __builtin_amdgcn_mfma_f32_16x16x32_bf16(ai, cil[ni], acc[mi][ni], 0, 0, 0);
            }
        }
        __syncthreads();
    }

#pragma unroll
    for (int mi = 0; mi < 4; ++mi)
#pragma unroll
        for (int ni = 0; ni < 4; ++ni) {
            int lb = l0 + wl * 64 + mi * 16 + g * 4;
            int h = wh * 64 + ni * 16 + fr;
#pragma unroll
            for (int r = 0; r < 4; ++r) {
                size_t idx = ((size_t)b * LEN + lb + r) * HID + h;
                out[idx] = acc[mi][ni][r] + bf2f(ubf[idx]) * dv[ni];
            }
        }
}

// ---------------------------------------------------------------------------
// Workspace layout (bytes):
//   [0, 67108864)              2 bf16 state planes [re, im]
//   [67108864, 67110912)       lam (512 f32)
//   [67110912, 67373056)       B split planes (4 x 32768 ushort)
//   [67373056, 67635200)       C split planes (4 x 32768 ushort)
//   [67635200, 84412416)       ubf: u as bf16 [b][l][h]
// ---------------------------------------------------------------------------
extern "C" void kernel_launch(void* const* d_in, const int* in_sizes, int n_in,
                              void* d_out, int out_size, void* d_ws, size_t ws_size,
                              hipStream_t stream) {
    const float* u  = (const float*)d_in[0];
    const float* A  = (const float*)d_in[1];
    const float* G  = (const float*)d_in[2];
    const float* st = (const float*)d_in[3];
    const float* B  = (const float*)d_in[4];
    const float* C  = (const float*)d_in[5];
    const float* D  = (const float*)d_in[6];
    float* out = (float*)d_out;

    char* WS = (char*)d_ws;
    unsigned short* planes = (unsigned short*)WS;
    float* lam             = (float*)(WS + 67108864);
    unsigned short* Bsp    = (unsigned short*)(WS + 67110912);
    unsigned short* Csp    = (unsigned short*)(WS + 67373056);
    unsigned short* ubf    = (unsigned short*)(WS + 67635200);

    k0b_prep<<<257, 256, 0, stream>>>(B, C, A, G, st, Bsp, Csp, lam);
    ku_cvt<<<2048, 256, 0, stream>>>(u, ubf);
    k12_fused<<<512, 512, 0, stream>>>(ubf, Bsp, lam, planes);
    k3_out<<<512, 256, 0, stream>>>(planes, Csp, ubf, D, out);
}